// Round 12
// baseline (222.417 us; speedup 1.0000x reference)
//
#include <hip/hip_runtime.h>
#include <math.h>

#define DIM 256
#define NCROPS 10
#define EPSF 1e-8f

typedef short bf16x8 __attribute__((ext_vector_type(8)));
typedef float f32x4 __attribute__((ext_vector_type(4)));

// manual RNE f32->bf16 (values here are normal, no NaN/Inf)
__device__ __forceinline__ unsigned short f32_to_bf16(float x) {
  unsigned u = __float_as_uint(x);
  u += 0x7FFFu + ((u >> 16) & 1u);
  return (unsigned short)(u >> 16);
}

// ---------------------------------------------------------------------------
// Kernel 1: row-wise L2 normalize + zero keys/out (folds the two memsets).
// 4 waves/block, 8 rows per wave; float4 loads; butterfly reduce; writes
// f32 Xn (exact distance recompute) and bf16 Xb (MFMA Gram).
// ---------------------------------------------------------------------------
__global__ __launch_bounds__(256) void normalize_k(const float* __restrict__ X,
                                                   float* __restrict__ Xn,
                                                   unsigned short* __restrict__ Xb,
                                                   unsigned long long* __restrict__ keys,
                                                   float* __restrict__ out) {
  // zero this block's 32 keys (runs before mfma_argmax_k in stream order)
  if (threadIdx.x < 32) keys[blockIdx.x * 32 + threadIdx.x] = 0ull;
  if (blockIdx.x == 0 && threadIdx.x == 0) out[0] = 0.f;

  const int lane = threadIdx.x & 63;
  const int wave = threadIdx.x >> 6;
  const int w = blockIdx.x * 4 + wave;
#pragma unroll
  for (int rr = 0; rr < 8; ++rr) {
    const int row = w * 8 + rr;
    const float4 v = *(const float4*)(X + (size_t)row * DIM + lane * 4);
    float sq = v.x * v.x + v.y * v.y + v.z * v.z + v.w * v.w;
#pragma unroll
    for (int off = 32; off > 0; off >>= 1) sq += __shfl_xor(sq, off, 64);
    const float scale = 1.0f / fmaxf(sqrtf(sq), EPSF);
    float4 o;
    o.x = v.x * scale; o.y = v.y * scale; o.z = v.z * scale; o.w = v.w * scale;
    *(float4*)(Xn + (size_t)row * DIM + lane * 4) = o;
    ushort4 ob;
    ob.x = f32_to_bf16(o.x); ob.y = f32_to_bf16(o.y);
    ob.z = f32_to_bf16(o.z); ob.w = f32_to_bf16(o.w);
    *(ushort4*)(Xb + (size_t)row * DIM + lane * 4) = ob;
  }
}

// ---------------------------------------------------------------------------
// Kernel 2: bf16 MFMA Gram (Xb @ Xb^T) fused with per-row argmax (diag excl).
// SYMMETRY-HALVED via triangular 1-D grid (2080 blocks, no early-exit waste);
// T14 register double-buffer: kt+1 global loads issued before compute(kt) so
// HBM/L2 latency hides under MFMA. 128x128 tile, 4 waves each owning 64x64;
// K staged in 4 chunks of 64 (LDS 2 x 16 KB, XOR-swizzled rows, verified
// conflict-free). mfma_f32_16x16x32_bf16; C/D: col=lane&15, row=(lane>>4)*4+reg.
// Dual epilogue (row-max -> keys[row]; col-max -> keys[col]) verified r10
// (absmax 0.0). Key = (sortable_f32<<32) | ~index.
// ---------------------------------------------------------------------------
__device__ __forceinline__ unsigned long long shfl_xor_u64(unsigned long long x, int mask) {
  unsigned lo = (unsigned)x;
  unsigned hi = (unsigned)(x >> 32);
  lo = (unsigned)__shfl_xor((int)lo, mask, 64);
  hi = (unsigned)__shfl_xor((int)hi, mask, 64);
  return ((unsigned long long)hi << 32) | (unsigned long long)lo;
}

__device__ __forceinline__ unsigned long long umax64(unsigned long long a, unsigned long long b) {
  return a > b ? a : b;
}

__device__ __forceinline__ unsigned long long pack_key(float v, int idx) {
  const unsigned u = __float_as_uint(v);
  const unsigned s = (u & 0x80000000u) ? ~u : (u | 0x80000000u);
  return ((unsigned long long)s << 32) |
         (unsigned long long)(0xFFFFFFFFu - (unsigned)idx);
}

__global__ __launch_bounds__(256) void mfma_argmax_k(
    const unsigned short* __restrict__ Xb, unsigned long long* __restrict__ keys) {
  // triangular decode: t -> (by, bx) with bx >= by
  const int t = blockIdx.x;
  int r = (int)((sqrt(8.0 * (double)t + 1.0) - 1.0) * 0.5);
  while ((r + 1) * (r + 2) / 2 <= t) ++r;
  while (r * (r + 1) / 2 > t) --r;
  const int bx = r;
  const int by = t - r * (r + 1) / 2;

  __shared__ char As[16384];
  __shared__ char Bs[16384];

  const int tid = threadIdx.x;
  const int lane = tid & 63;
  const int wave = tid >> 6;
  const int wr = (wave >> 1) * 64;
  const int wc = (wave & 1) * 64;
  const int rowBase = by * 128;
  const int colBase = bx * 128;

  f32x4 acc[4][4];
#pragma unroll
  for (int m = 0; m < 4; ++m)
#pragma unroll
    for (int n = 0; n < 4; ++n) acc[m][n] = (f32x4){0.f, 0.f, 0.f, 0.f};

  const char* gA = (const char*)Xb + (size_t)rowBase * DIM * 2;
  const char* gB = (const char*)Xb + (size_t)colBase * DIM * 2;

  // per-thread staging coords (constant across kt): 4 chunks per panel
  int cdst[4];
  size_t gsrc[4];
#pragma unroll
  for (int i = 0; i < 4; ++i) {
    const int c = tid + 256 * i;
    const int row = c >> 3;
    const int kc = c & 7;
    cdst[i] = (row * 128 + kc * 16) ^ ((row & 7) << 4);
    gsrc[i] = ((size_t)row * DIM + kc * 8) * 2;  // + kt*128 bytes per chunk
  }

  // T14 double-buffer: prologue loads kt=0
  float4 ra[2][4], rb[2][4];
#pragma unroll
  for (int i = 0; i < 4; ++i) {
    ra[0][i] = *(const float4*)(gA + gsrc[i]);
    rb[0][i] = *(const float4*)(gB + gsrc[i]);
  }

#pragma unroll
  for (int kt = 0; kt < 4; ++kt) {
    const int cur = kt & 1;
    // issue next-chunk loads BEFORE compute: latency hides under MFMA
    if (kt < 3) {
#pragma unroll
      for (int i = 0; i < 4; ++i) {
        ra[cur ^ 1][i] = *(const float4*)(gA + gsrc[i] + (size_t)(kt + 1) * 128);
        rb[cur ^ 1][i] = *(const float4*)(gB + gsrc[i] + (size_t)(kt + 1) * 128);
      }
    }
    // LDS write of current chunk (swizzled dest)
#pragma unroll
    for (int i = 0; i < 4; ++i) {
      *(float4*)(As + cdst[i]) = ra[cur][i];
      *(float4*)(Bs + cdst[i]) = rb[cur][i];
    }
    __syncthreads();

#pragma unroll
    for (int ks = 0; ks < 2; ++ks) {
      const int kbyte = ks * 64 + ((lane >> 4) << 4);
      bf16x8 a[4], b[4];
#pragma unroll
      for (int m = 0; m < 4; ++m) {
        const int rr = wr + m * 16 + (lane & 15);
        a[m] = *(const bf16x8*)(As + ((rr * 128 + kbyte) ^ ((rr & 7) << 4)));
      }
#pragma unroll
      for (int n = 0; n < 4; ++n) {
        const int rr = wc + n * 16 + (lane & 15);
        b[n] = *(const bf16x8*)(Bs + ((rr * 128 + kbyte) ^ ((rr & 7) << 4)));
      }
#pragma unroll
      for (int m = 0; m < 4; ++m)
#pragma unroll
        for (int n = 0; n < 4; ++n)
          acc[m][n] = __builtin_amdgcn_mfma_f32_16x16x32_bf16(a[m], b[n], acc[m][n], 0, 0, 0);
    }
    if (kt < 3) __syncthreads();  // protect LDS against next iteration's writes
  }

  const int rfb = (lane >> 4) * 4;

  // ---- row-epilogue: per-row argmax over this wave's 64 cols -> keys[row]
#pragma unroll
  for (int m = 0; m < 4; ++m) {
#pragma unroll
    for (int r2 = 0; r2 < 4; ++r2) {
      const int grow = rowBase + wr + m * 16 + rfb + r2;
      unsigned long long best = 0ull;
#pragma unroll
      for (int n = 0; n < 4; ++n) {
        const int gcol = colBase + wc + n * 16 + (lane & 15);
        float v = acc[m][n][r2];
        if (gcol == grow) v = -2.0f;
        best = umax64(best, pack_key(v, gcol));
      }
#pragma unroll
      for (int off = 1; off < 16; off <<= 1) best = umax64(best, shfl_xor_u64(best, off));
      if ((lane & 15) == 0) atomicMax(keys + grow, best);
    }
  }

  // ---- col-epilogue: per-col argmax over this wave's 64 rows -> keys[col]
#pragma unroll
  for (int n = 0; n < 4; ++n) {
    const int gcol = colBase + wc + n * 16 + (lane & 15);
    unsigned long long best = 0ull;
#pragma unroll
    for (int m = 0; m < 4; ++m) {
#pragma unroll
      for (int r2 = 0; r2 < 4; ++r2) {
        const int grow = rowBase + wr + m * 16 + rfb + r2;
        float v = acc[m][n][r2];
        if (gcol == grow) v = -2.0f;
        best = umax64(best, pack_key(v, grow));
      }
    }
    best = umax64(best, shfl_xor_u64(best, 16));
    best = umax64(best, shfl_xor_u64(best, 32));
    if (lane < 16) atomicMax(keys + gcol, best);
  }
}

// ---------------------------------------------------------------------------
// Kernel 3: per-row NN distance (exact reference arithmetic on f32 Xn:
// x - x[I] + eps elementwise, sqrt, log). 4 waves/block, 8 rows per wave;
// float4 loads; lane0 accumulates -log across rows; ONE atomicAdd per block.
// ---------------------------------------------------------------------------
__global__ __launch_bounds__(256) void finish_k(const float* __restrict__ Xn,
                                                const unsigned long long* __restrict__ keys,
                                                float* __restrict__ out, int n) {
  const int lane = threadIdx.x & 63;
  const int wave = threadIdx.x >> 6;
  const int w = blockIdx.x * 4 + wave;
  float acc = 0.f;
#pragma unroll
  for (int rr = 0; rr < 8; ++rr) {
    const int row = w * 8 + rr;
    const unsigned long long key = keys[row];
    const int I = (int)(0xFFFFFFFFu - (unsigned)(key & 0xFFFFFFFFull));
    const float4 a = *(const float4*)(Xn + (size_t)row * DIM + lane * 4);
    const float4 b = *(const float4*)(Xn + (size_t)I * DIM + lane * 4);
    const float dx = a.x - b.x + EPSF;
    const float dy = a.y - b.y + EPSF;
    const float dz = a.z - b.z + EPSF;
    const float dw = a.w - b.w + EPSF;
    float s = dx * dx + dy * dy + dz * dz + dw * dw;
#pragma unroll
    for (int off = 32; off > 0; off >>= 1) s += __shfl_xor(s, off, 64);
    if (lane == 0) acc += -logf(sqrtf(s) + EPSF);
  }
  __shared__ float parts[4];
  if (lane == 0) parts[wave] = acc;
  __syncthreads();
  if (threadIdx.x == 0) {
    atomicAdd(out, (parts[0] + parts[1] + parts[2] + parts[3]) / (float)n);
  }
}

// ---------------------------------------------------------------------------
extern "C" void kernel_launch(void* const* d_in, const int* in_sizes, int n_in,
                              void* d_out, int out_size, void* d_ws, size_t ws_size,
                              hipStream_t stream) {
  const float* X = (const float*)d_in[0];
  float* out = (float*)d_out;

  const int n = in_sizes[0] / (DIM * NCROPS);  // 8192

  float* Xn = (float*)d_ws;                                             // 8 MB
  unsigned short* Xb =
      (unsigned short*)((char*)d_ws + (size_t)n * DIM * sizeof(float));  // 4 MB
  unsigned long long* keys =
      (unsigned long long*)((char*)d_ws + (size_t)n * DIM * 6);          // 64 KB

  const int rows_per_block = 32;  // 4 waves x 8 rows
  normalize_k<<<n / rows_per_block, 256, 0, stream>>>(X, Xn, Xb, keys, out);

  const int ntiles = n / 128;                       // 64
  const int nblk = ntiles * (ntiles + 1) / 2;       // 2080 upper-tri tiles
  mfma_argmax_k<<<nblk, 256, 0, stream>>>(Xb, keys);

  finish_k<<<n / rows_per_block, 256, 0, stream>>>(Xn, keys, out, n);
}